// Round 1
// baseline (3053.657 us; speedup 1.0000x reference)
//
#include <hip/hip_runtime.h>

// Kalman filter, B=256 T=512 S=64 M=32.
// Key structure: covariance/gain recursion is batch-independent -> compute once
// (kernel 1, single WG), then 256 independent per-batch linear state recursions
// (kernel 2, one wave per batch).

#define Sdim 64
#define Mdim 32
#define Tdim 512
#define Bdim 256

#define NEWTON_TOL 5e-4f   // max|I - Sm*Y| target (fp32 residual floor ~1e-4)
#define DK_TOL     2e-5f   // gain stationarity threshold (freeze K afterwards)
#define MIN_STEPS  16

// ---------------------------------------------------------------------------
// Kernel 1: Riccati recursion, single workgroup of 1024 threads.
// Writes K'_t = Sm_t^{-1} (H P_t) [Mdim x Sdim] per step into K_all,
// t_star (last computed step; K frozen afterwards) into tstar_out,
// and F^T into FT (for bank/coalescing-friendly access in phase g).
// ---------------------------------------------------------------------------
__global__ __launch_bounds__(1024)
void riccati_kernel(const float* __restrict__ F, const float* __restrict__ H,
                    const float* __restrict__ Q, const float* __restrict__ R,
                    const float* __restrict__ P0,
                    float* __restrict__ K_all, int* __restrict__ tstar_out,
                    float* __restrict__ FT)
{
    __shared__ float Ps [Sdim*Sdim];  // 16 KB: predicted covariance at loop top
    __shared__ float Gs [Sdim*Sdim];  // 16 KB: scratch (F*P, Newton Ynew)
    __shared__ float HPs[Mdim*Sdim];  //  8 KB
    __shared__ float Sms[Mdim*Mdim];  //  4 KB
    __shared__ float Ys [Mdim*Mdim];  //  4 KB: running inverse of Sm
    __shared__ float T1s[Mdim*Mdim];  //  4 KB: Sm*Y
    __shared__ float Kps[Mdim*Sdim];  //  8 KB: K' (previous step kept for delta)
    __shared__ int   red_i;           // atomicMax reduction (float-as-int, >=0)
    __shared__ int   restarted;

    const int tid = threadIdx.x;

    // FT[k][l] = F[l][k]; load P0
    for (int i = tid; i < Sdim*Sdim; i += 1024) {
        int k = i >> 6, l = i & 63;
        FT[i] = F[l*Sdim + k];
    }
    for (int i = tid; i < Sdim*Sdim; i += 1024) Ps[i] = P0[i];
    __syncthreads();

    // initial predict: P = F P0 F^T + Q
    for (int i = tid; i < Sdim*Sdim; i += 1024) {
        int r = i >> 6, s = i & 63;
        float acc = 0.f;
        #pragma unroll 8
        for (int k = 0; k < Sdim; ++k) acc += F[r*Sdim+k] * Ps[k*Sdim+s];
        Gs[i] = acc;
    }
    __syncthreads();
    for (int i = tid; i < Sdim*Sdim; i += 1024) {
        int r = i >> 6, l = i & 63;
        float acc = Q[i];
        #pragma unroll 8
        for (int k = 0; k < Sdim; ++k) acc += Gs[r*Sdim+k] * FT[k*Sdim+l];
        Ps[i] = acc;
    }
    __syncthreads();

    int tstar = Tdim - 1;

    for (int t = 0; t < Tdim; ++t) {
        // --- a: HP = H * P  [32x64]
        for (int i = tid; i < Mdim*Sdim; i += 1024) {
            int m = i >> 6, s = i & 63;
            float acc = 0.f;
            #pragma unroll 8
            for (int k = 0; k < Sdim; ++k) acc += H[m*Sdim+k] * Ps[k*Sdim+s];
            HPs[i] = acc;
        }
        __syncthreads();
        // --- b: Sm = HP * H^T + R  [32x32]
        {
            int m = tid >> 5, n = tid & 31;
            float acc = R[m*Mdim+n];
            #pragma unroll 8
            for (int s = 0; s < Sdim; ++s) acc += HPs[m*Sdim+s] * H[n*Sdim+s];
            Sms[tid] = acc;
            if (tid == 0) restarted = 0;
        }
        __syncthreads();

        // --- Newton-Schulz init (t==0): Y = I / max_row_sum(Sm)
        if (t == 0) {
            if (tid == 0) red_i = 0;
            __syncthreads();
            if (tid < Mdim) {
                float rs = 0.f;
                for (int j = 0; j < Mdim; ++j) rs += fabsf(Sms[tid*Mdim+j]);
                atomicMax(&red_i, __float_as_int(rs));
            }
            __syncthreads();
            float inv = 1.0f / __int_as_float(red_i);
            { int i2 = tid >> 5, j2 = tid & 31; Ys[tid] = (i2 == j2) ? inv : 0.f; }
            __syncthreads();
        }

        // --- Newton-Schulz: refine Y ~= Sm^{-1}, check-first (Y untouched once
        // converged -> bit-stable K' -> exact-zero delta at stationarity)
        for (int it = 0; it < 40; ++it) {
            if (tid == 0) red_i = 0;
            __syncthreads();
            {
                int i2 = tid >> 5, j2 = tid & 31;
                float acc = 0.f;
                #pragma unroll 8
                for (int k = 0; k < Mdim; ++k) acc += Sms[i2*Mdim+k] * Ys[k*Mdim+j2];
                T1s[tid] = acc;
                float e = fabsf(((i2 == j2) ? 1.f : 0.f) - acc);
                atomicMax(&red_i, __float_as_int(e));
            }
            __syncthreads();
            float resid = __int_as_float(red_i);        // uniform
            if (resid < NEWTON_TOL) break;
            bool bad = !(resid < 1e30f);                // NaN/Inf or divergence
            if ((bad || (it >= 12 && resid > 0.9f)) && restarted == 0) {
                // rescue: fresh re-init from current Sm
                if (tid == 0) red_i = 0;
                __syncthreads();
                if (tid < Mdim) {
                    float rs = 0.f;
                    for (int j = 0; j < Mdim; ++j) rs += fabsf(Sms[tid*Mdim+j]);
                    atomicMax(&red_i, __float_as_int(rs));
                }
                __syncthreads();
                float inv = 1.0f / __int_as_float(red_i);
                { int i2 = tid >> 5, j2 = tid & 31; Ys[tid] = (i2 == j2) ? inv : 0.f; }
                if (tid == 0) restarted = 1;
                __syncthreads();
                continue;
            }
            // Ynew = 2Y - Y*T1 (scratch in Gs), then copy back
            {
                int i2 = tid >> 5, j2 = tid & 31;
                float acc = 2.f * Ys[tid];
                #pragma unroll 8
                for (int k = 0; k < Mdim; ++k) acc -= Ys[i2*Mdim+k] * T1s[k*Mdim+j2];
                Gs[tid] = acc;
            }
            __syncthreads();
            Ys[tid] = Gs[tid];
            __syncthreads();
        }

        // --- d: K' = Y * HP [32x64]; store to global; delta vs previous step
        if (tid == 0) red_i = 0;
        __syncthreads();
        for (int i = tid; i < Mdim*Sdim; i += 1024) {
            int m = i >> 6, s = i & 63;
            float acc = 0.f;
            #pragma unroll 8
            for (int n = 0; n < Mdim; ++n) acc += Ys[m*Mdim+n] * HPs[n*Sdim+s];
            float d = fabsf(acc - Kps[i]);
            atomicMax(&red_i, __float_as_int(d));
            Kps[i] = acc;
            K_all[(size_t)t*(Mdim*Sdim) + i] = acc;
        }
        __syncthreads();
        float dK = __int_as_float(red_i);               // uniform

        // --- e: P -= K'^T * HP   (P[r][s] -= sum_m K'[m][r]*HP[m][s]; own-element in place)
        for (int i = tid; i < Sdim*Sdim; i += 1024) {
            int r = i >> 6, s = i & 63;
            float acc = Ps[i];
            #pragma unroll 8
            for (int m = 0; m < Mdim; ++m) acc -= Kps[m*Sdim+r] * HPs[m*Sdim+s];
            Ps[i] = acc;
        }
        __syncthreads();

        // --- convergence freeze: gain stationary -> remaining K_t identical to fp32 noise
        if (t >= MIN_STEPS && dK < DK_TOL) { tstar = t; break; }

        // --- f: G = F * P_upd
        for (int i = tid; i < Sdim*Sdim; i += 1024) {
            int r = i >> 6, s = i & 63;
            float acc = 0.f;
            #pragma unroll 8
            for (int k = 0; k < Sdim; ++k) acc += F[r*Sdim+k] * Ps[k*Sdim+s];
            Gs[i] = acc;
        }
        __syncthreads();
        // --- g: P = G * F^T + Q   (FT gives coalesced per-lane access)
        for (int i = tid; i < Sdim*Sdim; i += 1024) {
            int r = i >> 6, l = i & 63;
            float acc = Q[i];
            #pragma unroll 8
            for (int k = 0; k < Sdim; ++k) acc += Gs[r*Sdim+k] * FT[k*Sdim+l];
            Ps[i] = acc;
        }
        __syncthreads();
    }
    if (tid == 0) *tstar_out = tstar;
}

// ---------------------------------------------------------------------------
// Kernel 2: per-batch state recursion. One wave (64 lanes) per batch,
// 4 waves per block. Lane l holds x[l]; F row l and H row (l&31) in VGPRs;
// cross-lane broadcasts via __shfl; K'_t streamed coalesced from workspace.
// ---------------------------------------------------------------------------
__global__ __launch_bounds__(256)
void filter_kernel(const float* __restrict__ obs, const float* __restrict__ F,
                   const float* __restrict__ H, const float* __restrict__ x0,
                   const float* __restrict__ K_all, const int* __restrict__ tstar_p,
                   float* __restrict__ out)
{
    const int lane = threadIdx.x & 63;
    const int wv   = threadIdx.x >> 6;
    const int b    = blockIdx.x * 4 + wv;
    const int m    = lane & 31;

    float Fr[Sdim];
    #pragma unroll
    for (int j = 0; j < Sdim; ++j) Fr[j] = F[lane*Sdim + j];
    float Hr[Sdim];
    #pragma unroll
    for (int j = 0; j < Sdim; ++j) Hr[j] = H[m*Sdim + j];

    const int tstar = *tstar_p;

    // x = F * x0  (initial predict)
    float x;
    {
        float a0 = 0.f, a1 = 0.f, a2 = 0.f, a3 = 0.f;
        #pragma unroll
        for (int j = 0; j < 16; ++j) {
            a0 += Fr[j]      * x0[j];
            a1 += Fr[j + 16] * x0[j + 16];
            a2 += Fr[j + 32] * x0[j + 32];
            a3 += Fr[j + 48] * x0[j + 48];
        }
        x = (a0 + a1) + (a2 + a3);
    }

    const float* __restrict__ obs_b = obs + (size_t)b * (Tdim*Mdim);
    float*       __restrict__ out_b = out + (size_t)b * (Tdim*Mdim);

    for (int t = 0; t < Tdim; ++t) {
        // z[m] = sum_j H[m][j] x[j]  (computed twice, once per wave half)
        float z;
        {
            float a0 = 0.f, a1 = 0.f, a2 = 0.f, a3 = 0.f;
            #pragma unroll
            for (int j = 0; j < 16; ++j) {
                a0 += Hr[j]      * __shfl(x, j, 64);
                a1 += Hr[j + 16] * __shfl(x, j + 16, 64);
                a2 += Hr[j + 32] * __shfl(x, j + 32, 64);
                a3 += Hr[j + 48] * __shfl(x, j + 48, 64);
            }
            z = (a0 + a1) + (a2 + a3);
        }
        float o = obs_b[t*Mdim + m];
        float resid = o - z;
        if (lane < Mdim) out_b[t*Mdim + lane] = z;

        const int kt = t < tstar ? t : tstar;
        const float* __restrict__ Kt = K_all + (size_t)kt * (Mdim*Sdim);

        // u = x + sum_m K'[m][lane] * resid[m]
        float u = x;
        {
            float a0 = 0.f, a1 = 0.f;
            #pragma unroll
            for (int mm = 0; mm < 16; ++mm) {
                a0 += Kt[mm*Sdim + lane]        * __shfl(resid, mm, 64);
                a1 += Kt[(mm + 16)*Sdim + lane] * __shfl(resid, mm + 16, 64);
            }
            u += a0 + a1;
        }
        // x = F * u
        {
            float a0 = 0.f, a1 = 0.f, a2 = 0.f, a3 = 0.f;
            #pragma unroll
            for (int j = 0; j < 16; ++j) {
                a0 += Fr[j]      * __shfl(u, j, 64);
                a1 += Fr[j + 16] * __shfl(u, j + 16, 64);
                a2 += Fr[j + 32] * __shfl(u, j + 32, 64);
                a3 += Fr[j + 48] * __shfl(u, j + 48, 64);
            }
            x = (a0 + a1) + (a2 + a3);
        }
    }
}

// ---------------------------------------------------------------------------
extern "C" void kernel_launch(void* const* d_in, const int* in_sizes, int n_in,
                              void* d_out, int out_size, void* d_ws, size_t ws_size,
                              hipStream_t stream)
{
    const float* obs = (const float*)d_in[0];
    const float* F   = (const float*)d_in[1];
    const float* H   = (const float*)d_in[2];
    const float* Q   = (const float*)d_in[3];
    const float* R   = (const float*)d_in[4];
    const float* x0  = (const float*)d_in[5];
    const float* P0  = (const float*)d_in[6];
    float* out = (float*)d_out;

    // workspace layout: K_all (512*32*64 f32 = 4 MiB) | tstar (int) | FT (64*64 f32)
    float* K_all = (float*)d_ws;
    char*  base  = (char*)d_ws + (size_t)Tdim * Mdim * Sdim * sizeof(float);
    int*   tst   = (int*)base;
    float* FT    = (float*)(base + 256);

    hipLaunchKernelGGL(riccati_kernel, dim3(1), dim3(1024), 0, stream,
                       F, H, Q, R, P0, K_all, tst, FT);
    hipLaunchKernelGGL(filter_kernel, dim3(64), dim3(256), 0, stream,
                       obs, F, H, x0, K_all, tst, out);
}

// Round 2
// 2153.261 us; speedup vs baseline: 1.4182x; 1.4182x over previous
//
#include <hip/hip_runtime.h>

// Kalman filter, B=256 T=512 S=64 M=32.
// Kernel 1 (single WG): batch-independent Riccati/gain recursion, publishing
// K'_t per step via device-scope flags; freezes when the gain is stationary.
// Kernel 2 (256 waves, one per batch): linear state recursion consuming K'_t
// as produced (producer-consumer overlap).

#define Sdim 64
#define Mdim 32
#define Tdim 512

#define NEWTON_TOL 1.5e-4f
#define DK_TOL     1.5e-4f
#define MIN_STEPS  48

typedef float f4 __attribute__((ext_vector_type(4)));

__global__ __launch_bounds__(1024)
void riccati_kernel(const float* __restrict__ F, const float* __restrict__ H,
                    const float* __restrict__ Q, const float* __restrict__ R,
                    const float* __restrict__ P0,
                    float* __restrict__ K_all, unsigned int* __restrict__ flags,
                    int* __restrict__ tstar_out)
{
    __shared__ __align__(16) float Ps [64*64];
    __shared__ __align__(16) float Gs [64*68];
    __shared__ __align__(16) float HPs[32*64];
    __shared__ __align__(16) float Hs [32*65+4];
    __shared__ __align__(16) float Fs [64*65+4];
    __shared__ __align__(16) float FTs[64*64];
    __shared__ __align__(16) float Sms[32*33+4];
    __shared__ __align__(16) float Ys [32*33+4];
    __shared__ __align__(16) float T1s[32*33+4];
    __shared__ __align__(16) float Yns[32*33+4];
    __shared__ __align__(16) float Kp4[32*64];
    __shared__ __align__(16) float KpT[64*33+4];
    __shared__ int red_a, red_b, restarted;

    const int tid = threadIdx.x;
    f4* Ps4  = (f4*)Ps;
    f4* Gs4  = (f4*)Gs;
    f4* HP4  = (f4*)HPs;
    f4* FT4  = (f4*)FTs;
    f4* Kp44 = (f4*)Kp4;
    f4* K_all4 = (f4*)K_all;
    const f4* Q4 = (const f4*)Q;

    for (int i = tid; i < 64*64; i += 1024) {
        int r = i >> 6, c = i & 63;
        float v = F[i];
        Fs[r*65 + c] = v;
        FTs[c*64 + r] = v;
        Ps[i] = P0[i];
    }
    for (int i = tid; i < 32*64; i += 1024) {
        int mm = i >> 6, c = i & 63;
        Hs[mm*65 + c] = H[i];
    }
    __syncthreads();

    const int r16 = tid >> 4, j16 = tid & 15;
    const int i32 = tid >> 5, j32 = tid & 31;

    { // initial predict: Ps = F P0 F^T + Q
        f4 acc = {0.f,0.f,0.f,0.f};
        #pragma unroll 8
        for (int k = 0; k < 64; ++k) acc += Fs[r16*65 + k] * Ps4[k*16 + j16];
        Gs4[r16*17 + j16] = acc;
    }
    __syncthreads();
    {
        f4 acc = Q4[r16*16 + j16];
        #pragma unroll 8
        for (int k = 0; k < 64; ++k) acc += Gs[r16*68 + k] * FT4[k*16 + j16];
        Ps4[r16*16 + j16] = acc;
    }
    __syncthreads();

    int tstar = Tdim - 1;

    for (int t = 0; t < Tdim; ++t) {
        if (tid < 512) {                       // a: HP = H * P
            int mm = tid >> 4, j = tid & 15;
            f4 acc = {0.f,0.f,0.f,0.f};
            #pragma unroll 8
            for (int k = 0; k < 64; ++k) acc += Hs[mm*65 + k] * Ps4[k*16 + j];
            HP4[mm*16 + j] = acc;
        }
        __syncthreads();
        {                                       // b: Sm = HP H^T + R
            float acc = R[i32*32 + j32];
            #pragma unroll 8
            for (int s = 0; s < 64; ++s) acc += HPs[i32*64 + s] * Hs[j32*65 + s];
            Sms[i32*33 + j32] = acc;
            if (tid == 0) { red_a = 0; red_b = 0; restarted = 0; }
        }
        __syncthreads();

        if (t == 0) {                           // Newton init
            if (tid < 32) {
                float rs = 0.f;
                for (int jj = 0; jj < 32; ++jj) rs += fabsf(Sms[tid*33 + jj]);
                atomicMax(&red_a, __float_as_int(rs));
            }
            __syncthreads();
            float inv = 1.0f / __int_as_float(red_a);
            Ys[i32*33 + j32] = (i32 == j32) ? inv : 0.f;
            if (tid == 0) red_a = 0;
            __syncthreads();
        }

        for (int it = 0; it < 40; ++it) {       // Newton-Schulz, check-first
            float acc = 0.f;
            #pragma unroll 8
            for (int k = 0; k < 32; ++k) acc += Sms[i32*33 + k] * Ys[k*33 + j32];
            T1s[i32*33 + j32] = acc;
            float e = fabsf(((i32 == j32) ? 1.f : 0.f) - acc);
            atomicMax(&red_a, __float_as_int(e));
            __syncthreads();
            float resid = __int_as_float(red_a);
            if (resid < NEWTON_TOL) break;
            bool bad = !(resid < 1e30f);
            if ((bad || (it >= 12 && resid > 0.9f)) && restarted == 0) {
                if (tid == 0) red_a = 0;
                __syncthreads();
                if (tid < 32) {
                    float rs = 0.f;
                    for (int jj = 0; jj < 32; ++jj) rs += fabsf(Sms[tid*33 + jj]);
                    atomicMax(&red_a, __float_as_int(rs));
                }
                __syncthreads();
                float inv = 1.0f / __int_as_float(red_a);
                Ys[i32*33 + j32] = (i32 == j32) ? inv : 0.f;
                if (tid == 0) { restarted = 1; red_a = 0; }
                __syncthreads();
                continue;
            }
            float up = 2.f * Ys[i32*33 + j32];
            #pragma unroll 8
            for (int k = 0; k < 32; ++k) up -= Ys[i32*33 + k] * T1s[k*33 + j32];
            Yns[i32*33 + j32] = up;
            if (tid == 0) red_a = 0;
            __syncthreads();
            Ys[i32*33 + j32] = Yns[i32*33 + j32];
            __syncthreads();
        }

        if (tid < 512) {                        // d: K' = Y * HP
            int mm = tid >> 4, j = tid & 15;
            f4 acc = {0.f,0.f,0.f,0.f};
            #pragma unroll 8
            for (int n = 0; n < 32; ++n) acc += Ys[mm*33 + n] * HP4[n*16 + j];
            f4 old = Kp44[mm*16 + j];
            float dm = fmaxf(fmaxf(fabsf(acc[0]-old[0]), fabsf(acc[1]-old[1])),
                             fmaxf(fabsf(acc[2]-old[2]), fabsf(acc[3]-old[3])));
            atomicMax(&red_b, __float_as_int(dm));
            Kp44[mm*16 + j] = acc;
            K_all4[(size_t)t*512 + tid] = acc;
            int s0 = j * 4;
            KpT[(s0    )*33 + mm] = acc[0];
            KpT[(s0 + 1)*33 + mm] = acc[1];
            KpT[(s0 + 2)*33 + mm] = acc[2];
            KpT[(s0 + 3)*33 + mm] = acc[3];
        }
        __syncthreads();                        // drains vmcnt -> K_t visible
        if (tid == 0)
            __hip_atomic_store(&flags[t], 1u, __ATOMIC_RELEASE, __HIP_MEMORY_SCOPE_AGENT);

        {                                       // e: P -= K'^T * HP
            f4 acc = Ps4[r16*16 + j16];
            #pragma unroll 8
            for (int mm = 0; mm < 32; ++mm) acc -= KpT[r16*33 + mm] * HP4[mm*16 + j16];
            Ps4[r16*16 + j16] = acc;
        }
        __syncthreads();

        float dK = __int_as_float(red_b);
        if (t >= MIN_STEPS && dK < DK_TOL) {    // freeze: gain stationary
            tstar = t;
            for (int tt = t + 1; tt < Tdim; ++tt)
                if (tid < 512) K_all4[(size_t)tt*512 + tid] = Kp44[tid];
            __syncthreads();
            for (int tt = t + 1 + tid; tt < Tdim; tt += 1024)
                __hip_atomic_store(&flags[tt], 1u, __ATOMIC_RELEASE, __HIP_MEMORY_SCOPE_AGENT);
            break;
        }

        {                                       // f: G = F * P_upd
            f4 acc = {0.f,0.f,0.f,0.f};
            #pragma unroll 8
            for (int k = 0; k < 64; ++k) acc += Fs[r16*65 + k] * Ps4[k*16 + j16];
            Gs4[r16*17 + j16] = acc;
        }
        __syncthreads();
        {                                       // g: P = G F^T + Q
            f4 acc = Q4[r16*16 + j16];
            #pragma unroll 8
            for (int k = 0; k < 64; ++k) acc += Gs[r16*68 + k] * FT4[k*16 + j16];
            Ps4[r16*16 + j16] = acc;
        }
        __syncthreads();
    }
    if (tid == 0) *tstar_out = tstar;
}

__global__ __launch_bounds__(256)
void filter_kernel(const float* __restrict__ obs, const float* __restrict__ F,
                   const float* __restrict__ H, const float* __restrict__ x0,
                   const float* __restrict__ K_all,
                   const unsigned int* __restrict__ flags,
                   float* __restrict__ out)
{
    const int lane = threadIdx.x & 63;
    const int wv   = threadIdx.x >> 6;
    const int b    = blockIdx.x * 4 + wv;
    const int m    = lane & 31;

    float Fr[Sdim];
    #pragma unroll
    for (int j = 0; j < Sdim; ++j) Fr[j] = F[lane*Sdim + j];
    float Hr[Sdim];
    #pragma unroll
    for (int j = 0; j < Sdim; ++j) Hr[j] = H[m*Sdim + j];

    float x;
    {
        float a0 = 0.f, a1 = 0.f, a2 = 0.f, a3 = 0.f;
        #pragma unroll
        for (int j = 0; j < 16; ++j) {
            a0 += Fr[j]      * x0[j];
            a1 += Fr[j + 16] * x0[j + 16];
            a2 += Fr[j + 32] * x0[j + 32];
            a3 += Fr[j + 48] * x0[j + 48];
        }
        x = (a0 + a1) + (a2 + a3);
    }

    const float* __restrict__ obs_b = obs + (size_t)b * (Tdim*Mdim);
    float*       __restrict__ out_b = out + (size_t)b * (Tdim*Mdim);

    float o = obs_b[m];
    bool tail_done = false;

    for (int t = 0; t < Tdim; ++t) {
        if (!tail_done) {
            if (__hip_atomic_load(&flags[Tdim-1], __ATOMIC_ACQUIRE,
                                  __HIP_MEMORY_SCOPE_AGENT) == 1u) {
                tail_done = true;
            } else {
                while (__hip_atomic_load(&flags[t], __ATOMIC_ACQUIRE,
                                         __HIP_MEMORY_SCOPE_AGENT) != 1u)
                    __builtin_amdgcn_s_sleep(2);
            }
        }
        const float* __restrict__ Kt = K_all + (size_t)t * (Mdim*Sdim);

        float kv[Mdim];
        #pragma unroll
        for (int mm = 0; mm < Mdim; ++mm) kv[mm] = Kt[mm*Sdim + lane];

        float z;
        {
            float a0 = 0.f, a1 = 0.f, a2 = 0.f, a3 = 0.f;
            #pragma unroll
            for (int j = 0; j < 16; ++j) {
                a0 += Hr[j]      * __shfl(x, j, 64);
                a1 += Hr[j + 16] * __shfl(x, j + 16, 64);
                a2 += Hr[j + 32] * __shfl(x, j + 32, 64);
                a3 += Hr[j + 48] * __shfl(x, j + 48, 64);
            }
            z = (a0 + a1) + (a2 + a3);
        }
        float resid = o - z;
        if (t < Tdim - 1) o = obs_b[(t+1)*Mdim + m];
        if (lane < Mdim) out_b[t*Mdim + lane] = z;

        float u = x;
        {
            float a0 = 0.f, a1 = 0.f;
            #pragma unroll
            for (int mm = 0; mm < 16; ++mm) {
                a0 += kv[mm]      * __shfl(resid, mm, 64);
                a1 += kv[mm + 16] * __shfl(resid, mm + 16, 64);
            }
            u += a0 + a1;
        }
        {
            float a0 = 0.f, a1 = 0.f, a2 = 0.f, a3 = 0.f;
            #pragma unroll
            for (int j = 0; j < 16; ++j) {
                a0 += Fr[j]      * __shfl(u, j, 64);
                a1 += Fr[j + 16] * __shfl(u, j + 16, 64);
                a2 += Fr[j + 32] * __shfl(u, j + 32, 64);
                a3 += Fr[j + 48] * __shfl(u, j + 48, 64);
            }
            x = (a0 + a1) + (a2 + a3);
        }
    }
}

extern "C" void kernel_launch(void* const* d_in, const int* in_sizes, int n_in,
                              void* d_out, int out_size, void* d_ws, size_t ws_size,
                              hipStream_t stream)
{
    const float* obs = (const float*)d_in[0];
    const float* F   = (const float*)d_in[1];
    const float* H   = (const float*)d_in[2];
    const float* Q   = (const float*)d_in[3];
    const float* R   = (const float*)d_in[4];
    const float* x0  = (const float*)d_in[5];
    const float* P0  = (const float*)d_in[6];
    float* out = (float*)d_out;

    const size_t K_BYTES = (size_t)Tdim * Mdim * Sdim * sizeof(float);
    float*        K_all = (float*)d_ws;
    unsigned int* flags = (unsigned int*)((char*)d_ws + K_BYTES);
    int*          tst   = (int*)((char*)d_ws + K_BYTES + Tdim*sizeof(unsigned int));

    hipMemsetAsync(flags, 0, Tdim*sizeof(unsigned int) + 64, stream);

    hipLaunchKernelGGL(riccati_kernel, dim3(1), dim3(1024), 0, stream,
                       F, H, Q, R, P0, K_all, flags, tst);
    hipLaunchKernelGGL(filter_kernel, dim3(64), dim3(256), 0, stream,
                       obs, F, H, x0, K_all, flags, out);
}